// Round 7
// baseline (130.781 us; speedup 1.0000x reference)
//
#include <hip/hip_runtime.h>

// WassersteinLoss: out = scale * sum_{b,c,t} |a-b| * (T - t)
// R6: barrier-free dual-path streaming. R5 proved vector-MSHR and LDS-DMA
// are separate per-CU outstanding-request pools (27us vs 40us single-path).
// Remaining tax: __syncthreads vmcnt(0) drain coupled both pools per iter.
// Now each wave DMAs its OWN LDS segment of b + vector-loads matching a,
// gated only by a wave-local s_waitcnt(0). Per-wave double-buffered LDS
// segments (each used once -> no WAR). No workgroup barrier in the loop.

#define T_MASK 8191
#define T_DIMF 8192.0f

#define FLOATS_PER_BLOCK 8192      // per array
#define WAVE_CHUNK 1024            // floats per wave per iteration (4 KB)
#define NITER 2                    // 4 waves * 1024 * 2 = 8192

typedef float vfloat4 __attribute__((ext_vector_type(4)));

__device__ __forceinline__ void load_lds16(const float* g, float* l) {
    __builtin_amdgcn_global_load_lds(
        (const __attribute__((address_space(1))) void*)g,
        (__attribute__((address_space(3))) void*)l,
        16 /*bytes per lane*/, 0 /*offset*/, 0 /*aux*/);
}

__global__ __launch_bounds__(256)
void wl_partial_kernel(const float* __restrict__ a,
                       const float* __restrict__ b,
                       float* __restrict__ partial) {
    // [buffer][wave][floats] — wave w iteration it uses buffer it (used once)
    __shared__ float ldsB[NITER][4][WAVE_CHUNK];   // 32 KB

    const int tid  = threadIdx.x;
    const int lane = tid & 63;
    const int wave = tid >> 6;                     // 0..3
    const int blockBase = blockIdx.x * FLOATS_PER_BLOCK;

    float acc = 0.0f;

    #pragma unroll
    for (int it = 0; it < NITER; ++it) {
        // this wave's 1024-float segment for this iteration
        const int segBase = blockBase + it * (4 * WAVE_CHUNK) + wave * WAVE_CHUNK;
        float* lseg = &ldsB[it][wave][0];

        // Path 1: DMA b-segment into this wave's LDS buffer.
        // 4 instrs x (64 lanes x 16 B) = 4 KB. LDS base wave-uniform.
        #pragma unroll
        for (int s = 0; s < 4; ++s)
            load_lds16(b + segBase + s * 256 + lane * 4, lseg + s * 256);

        // Path 2: nt vector loads of matching a-segment (4 float4/thread).
        vfloat4 xa[4];
        const vfloat4* a4 = (const vfloat4*)a;
        const int base4 = segBase >> 2;            // float4 index of segment
        #pragma unroll
        for (int s = 0; s < 4; ++s)
            xa[s] = __builtin_nontemporal_load(&a4[base4 + s * 64 + lane]);

        // Wave-local drain: waits this wave's DMA + vector loads only.
        __builtin_amdgcn_s_waitcnt(0);

        #pragma unroll
        for (int s = 0; s < 4; ++s) {
            vfloat4 y = ((const vfloat4*)lseg)[s * 64 + lane];
            const int g = (base4 + s * 64 + lane) * 4;   // global float idx of .x
            float w = T_DIMF - (float)(g & T_MASK);      // 4|T: no row wrap
            float d0 = fabsf(xa[s].x - y.x);
            float d1 = fabsf(xa[s].y - y.y);
            float d2 = fabsf(xa[s].z - y.z);
            float d3 = fabsf(xa[s].w - y.w);
            acc += w * (d0 + d1 + d2 + d3) - (d1 + 2.0f * d2 + 3.0f * d3);
        }
    }

    // wave-64 shuffle reduction
    #pragma unroll
    for (int off = 32; off > 0; off >>= 1)
        acc += __shfl_down(acc, off, 64);

    __shared__ float wave_sums[4];
    if (lane == 0) wave_sums[wave] = acc;
    __syncthreads();

    if (tid == 0)
        partial[blockIdx.x] = wave_sums[0] + wave_sums[1] + wave_sums[2] + wave_sums[3];
}

__global__ __launch_bounds__(256)
void wl_final_kernel(const float* __restrict__ partial, int n,
                     float* __restrict__ out, float scale) {
    float acc = 0.0f;
    for (int i = threadIdx.x; i < n; i += 256)
        acc += partial[i];

    #pragma unroll
    for (int off = 32; off > 0; off >>= 1)
        acc += __shfl_down(acc, off, 64);

    __shared__ float wave_sums[4];
    int lane = threadIdx.x & 63;
    int wave = threadIdx.x >> 6;
    if (lane == 0) wave_sums[wave] = acc;
    __syncthreads();

    if (threadIdx.x == 0)
        out[0] = (wave_sums[0] + wave_sums[1] + wave_sums[2] + wave_sums[3]) * scale;
}

extern "C" void kernel_launch(void* const* d_in, const int* in_sizes, int n_in,
                              void* d_out, int out_size, void* d_ws, size_t ws_size,
                              hipStream_t stream) {
    const float* a = (const float*)d_in[0];
    const float* b = (const float*)d_in[1];
    float* out = (float*)d_out;
    float* partial = (float*)d_ws;   // 2048 floats = 8 KB scratch

    int n = in_sizes[0];                     // 16,777,216
    int blocks = n / FLOATS_PER_BLOCK;       // 2048

    const long long T = 8192;
    const long long C = 64;
    const long long B = (long long)n / (C * T);
    float scale = (float)(2.0 / ((double)T * (double)C * (double)(T + 1) * (double)B));

    wl_partial_kernel<<<blocks, 256, 0, stream>>>(a, b, partial);
    wl_final_kernel<<<1, 256, 0, stream>>>(partial, blocks, out, scale);
}